// Round 11
// baseline (1102.672 us; speedup 1.0000x reference)
//
#include <hip/hip_runtime.h>
#include <hip/hip_bf16.h>
#include <hip/hip_fp16.h>

#define T_DIM 8192
#define H_DIM 3200
#define I_DIM 12800

typedef int v4i __attribute__((ext_vector_type(4)));
typedef _Float16 h8 __attribute__((ext_vector_type(8)));

__device__ __forceinline__ void gload16(const void* g, void* l) {
    __builtin_amdgcn_global_load_lds(
        (const __attribute__((address_space(1))) unsigned int*)g,
        (__attribute__((address_space(3))) unsigned int*)l, 16, 0, 0);
}

// ---------------- int32 -> int8 repack (memory-bound) ----------------
__global__ __launch_bounds__(256) void repack_kernel(const int* __restrict__ src,
                                                     unsigned int* __restrict__ dst,
                                                     long n4) {
    long i = (long)blockIdx.x * blockDim.x + threadIdx.x;
    long stride = (long)gridDim.x * blockDim.x;
    for (; i < n4; i += stride) {
        int4 v = ((const int4*)src)[i];
        dst[i] = (unsigned int)((v.x & 255) | ((v.y & 255) << 8) |
                                ((v.z & 255) << 16) | ((v.w & 255) << 24));
    }
}

// ---------------- i8 GEMM, C[M][N] = A[M][K] * B[N][K]^T ----------------
// R9's wave-level structure (per-wave 64x64, mfma_i32_16x16x64_i8, acc[4][4]
// = 64 AGPR + ~56 VGPR = 120 <= the 128-reg cap of 4 waves/SIMD) regrouped
// into TWO INDEPENDENT BLOCKS PER CU: 512 threads = 8 waves (2M x 4N),
// BM=128 x BN=256 tile, ring-of-3 LDS (A 3x8 KiB + B 3x16 KiB = 72 KiB ->
// 2 blocks/CU, 144 <= 160 KiB). Same 4 waves/SIMD as R9, but split across
// two unsynchronized blocks: when one block's waves converge at a barrier /
// vmcnt gate, the other block's waves fill the LDS port and MFMA pipe (m114
// co-schedule; R8's intent, now spill-free -- R8 spilled at 8 waves x
// 128x64/wave under the same reg cap). BN=256 keeps per-block arithmetic
// intensity at R9's level (R5's 128x128 regression was intensity loss).
// Phase (64-B K-half h): { 8 ds_read_b128 (af[4],bf[4]) ; STAGE half h+2
// (3 gload16/thread) into the rotate slot ; setprio1 ; 16 MFMA ; setprio0 ;
// vmcnt(3) ; ONE s_barrier ; rotate }.
// Ring-3 ledger: prologue stages halves 0,1 (6 loads), gate vmcnt(3) -> half
// 0 resident, half 1 in flight. Phase h stages h+2, gate retires half h+1,
// leaves h+2's 3 loads in flight -- never drained to 0. Slot safety (skew <=
// 1 phase): stage(h+2) targets the slot that was 'cur' at phase h-1; its
// readers' ds_reads completed (MFMA-consumed) before they crossed barrier
// h-1, which the stager has also crossed.
// LDS dest of global_load_lds is LINEAR; XOR swizzle (16B chunk
// cc ^= (row>>1)&3) pre-applied to per-lane GLOBAL source and ds_read addrs
// (0-conflict, measured). strideA/strideB in BYTES. EPI=0: fp16 out;
// EPI=1: fp32 of fp16-rounded. fc2's N=3200 runs on 13 col-guarded tiles;
// its 832-block grid over 512 co-resident slots also cuts the tail idle that
// the 416-block/256-slot config paid (19% -> ~8%).
// No XCD swizzle (L3-resident regime).
template <int EPI>
__global__ __launch_bounds__(512, 4) void gemm_i8_2cu(
    const signed char* __restrict__ A, long strideA,
    const signed char* __restrict__ B, long strideB,
    int Ntrue, int K, int ldc,
    const float* __restrict__ rowscale, const float* __restrict__ colscale,
    const float* __restrict__ bias, void* __restrict__ Cout) {
    __shared__ signed char lds[73728];
    signed char* ldsA = lds;           // 3 slots x 8192 B  (128 rows x 64 B)
    signed char* ldsB = lds + 24576;   // 3 slots x 16384 B (256 rows x 64 B)

    const int tid = threadIdx.x;
    const int lane = tid & 63, wid = tid >> 6;
    const int wr = wid >> 2, wc = wid & 3;
    const int bm = blockIdx.x, bn = blockIdx.y;
    const long Arow0 = (long)bm * 128;
    const long Bcol0 = (long)bn * 256;

    // Staging per half: A = 512 chunks of 16 B (1/thread), B = 1024 chunks
    // (2/thread: tid, tid+512). LDS dest linear (chunk*16); XOR swizzle
    // folded into the per-lane GLOBAL source chunk.
    const int rA = tid >> 2;
    const int sA = (((tid & 3) ^ ((rA >> 1) & 3)) << 4);
    const int rB1 = 128 + (tid >> 2);
    const int sB1 = (((tid & 3) ^ ((rB1 >> 1) & 3)) << 4);
    const signed char* Ag0 = A + (Arow0 + rA) * strideA + sA;
    const signed char* Bg0 = B + (Bcol0 + rA) * strideB + sA;
    const signed char* Bg1 = B + (Bcol0 + rB1) * strideB + sB1;
    const int dA = tid * 16, dB0 = tid * 16, dB1 = (tid + 512) * 16;

    const int NH = K >> 6;  // number of 64-byte K-halves (phases)

    // Stage half h into ring slot (byte offsets soA_/soB_ within regions).
#define STAGE(h, soA_, soB_)                        \
    {                                               \
        const int hc_ = (h) < NH ? (h) : NH - 1;    \
        const long ko_ = (long)hc_ << 6;            \
        gload16(Ag0 + ko_, ldsA + (soA_) + dA);     \
        gload16(Bg0 + ko_, ldsB + (soB_) + dB0);    \
        gload16(Bg1 + ko_, ldsB + (soB_) + dB1);    \
    }

    // Fragment read offsets: lane reads 16 B at (row, k-chunk q) -> LDS chunk
    // q ^ ((row>>1)&3); per-lane constant swz. Frag i lives at +i*1024.
    const int r = lane & 15, q = lane >> 4;
    const int swz = ((q ^ ((r >> 1) & 3)) << 4);
    const int aoff = (wr * 64 + r) * 64 + swz;  // + i*1024, i = 0..3 (A slot)
    const int boff = (wc * 64 + r) * 64 + swz;  // + n*1024, n = 0..3 (B slot)

    v4i acc[4][4] = {};
    v4i af[4], bf[4];

    // Prologue: stage halves 0,1 (6 loads); gate vmcnt(3) -> half 0 resident,
    // half 1 in flight.
    STAGE(0, 0, 0);
    STAGE(1, 8192, 16384);
    asm volatile("s_waitcnt vmcnt(3)");
    __builtin_amdgcn_s_barrier();

    int soAc = 0, soAn = 8192, soAs = 16384;
    int soBc = 0, soBn = 16384, soBs = 32768;
    for (int h = 0; h < NH; ++h) {
        const signed char* sAp = ldsA + soAc;
        const signed char* sBp = ldsB + soBc;
#pragma unroll
        for (int i = 0; i < 4; ++i) af[i] = *(const v4i*)(sAp + aoff + i * 1024);
#pragma unroll
        for (int n = 0; n < 4; ++n) bf[n] = *(const v4i*)(sBp + boff + n * 1024);
        // stage half h+2 into the rotate slot (phase h-1's 'cur'; its readers
        // drained before crossing barrier h-1, which we have also crossed).
        STAGE(h + 2, soAs, soBs);
        __builtin_amdgcn_s_setprio(1);
#pragma unroll
        for (int m = 0; m < 4; ++m)
#pragma unroll
            for (int n = 0; n < 4; ++n)
                acc[m][n] = __builtin_amdgcn_mfma_i32_16x16x64_i8(
                    af[m], bf[n], acc[m][n], 0, 0, 0);
        __builtin_amdgcn_s_setprio(0);
        // counted gate: retire half h+1's 3 loads; leave h+2's 3 in flight.
        asm volatile("s_waitcnt vmcnt(3)");
        __builtin_amdgcn_s_barrier();
        const int tA = soAc; soAc = soAn; soAn = soAs; soAs = tA;
        const int tB = soBc; soBc = soBn; soBn = soBs; soBs = tB;
    }

    // Epilogue: C/D layout col = lane&15, row = (lane>>4)*4 + reg.
    const int row0 = bm * 128 + wr * 64;
    const int col0 = bn * 256 + wc * 64;
    const int r4 = (lane >> 4) << 2, cl = lane & 15;
#pragma unroll
    for (int m = 0; m < 4; ++m) {
        const int rowb = row0 + m * 16 + r4;
        float rs[4];
#pragma unroll
        for (int rr = 0; rr < 4; ++rr) rs[rr] = rowscale[rowb + rr];
#pragma unroll
        for (int n = 0; n < 4; ++n) {
            const int col = col0 + n * 16 + cl;
            if (col < Ntrue) {
                const float cs = colscale[col];
                const float bs = bias[col];
#pragma unroll
                for (int rr = 0; rr < 4; ++rr) {
                    float v = (float)acc[m][n][rr];
                    v = __fmul_rn(v, rs[rr]);
                    v = __fmul_rn(v, cs);
                    v = __fadd_rn(v, bs);
                    _Float16 hh = (_Float16)v;  // reference rounds to fp16
                    const size_t idx = (size_t)(rowb + rr) * ldc + col;
                    if (EPI == 0) ((_Float16*)Cout)[idx] = hh;
                    else ((float*)Cout)[idx] = (float)hh;
                }
            }
        }
    }
#undef STAGE
}

// -------- exact GELU + per-token dynamic int8 requant (in-place act_q) -------
// 320 threads x 5 chunks of 8: g stays in registers (no gbuf LDS round-trip;
// all indices compile-time via full unroll). Reads complete before the
// __syncthreads; packed writes (first 12800 B of the row) happen after it.
__global__ __launch_bounds__(320) void gelu_quant(_Float16* __restrict__ fc1,
                                                  float* __restrict__ nscale) {
    __shared__ float wmax[5];
    const int tid = threadIdx.x, lane = tid & 63, wid = tid >> 6;
    const long t = blockIdx.x;
    const h8* row = (const h8*)(fc1 + t * I_DIM);
    float g[5][8];
    float lmax = 0.f;
#pragma unroll
    for (int k = 0; k < 5; ++k) {
        h8 v = row[tid + k * 320];
#pragma unroll
        for (int j = 0; j < 8; ++j) {
            float x = (float)v[j];
            // jax.nn.gelu exact: 0.5*x*(1+erf(x/sqrt(2))), no FMA contraction
            float e = erff(__fdiv_rn(x, 1.41421356237309504880f));
            float gg = __fmul_rn(__fmul_rn(0.5f, x), __fadd_rn(1.0f, e));
            g[k][j] = gg;
            lmax = fmaxf(lmax, fabsf(gg));
        }
    }
#pragma unroll
    for (int off = 32; off; off >>= 1) lmax = fmaxf(lmax, __shfl_xor(lmax, off, 64));
    if (lane == 0) wmax[wid] = lmax;
    __syncthreads();
    const float gmax = fmaxf(fmaxf(fmaxf(wmax[0], wmax[1]), fmaxf(wmax[2], wmax[3])),
                             wmax[4]);
    const float ns = gmax / 127.0f;
    if (tid == 0) nscale[t] = ns;
    unsigned long long* out = (unsigned long long*)(fc1 + t * I_DIM);  // in-place
#pragma unroll
    for (int k = 0; k < 5; ++k) {
        unsigned long long pk = 0;
#pragma unroll
        for (int j = 0; j < 8; ++j) {
            float qv = rintf(__fdiv_rn(g[k][j], ns));  // RNE == jnp.round
            qv = fminf(fmaxf(qv, -127.f), 127.f);
            pk |= ((unsigned long long)(unsigned char)(signed char)(int)qv) << (8 * j);
        }
        out[tid + k * 320] = pk;
    }
}

extern "C" void kernel_launch(void* const* d_in, const int* in_sizes, int n_in,
                              void* d_out, int out_size, void* d_ws, size_t ws_size,
                              hipStream_t stream) {
    const int* hs = (const int*)d_in[0];        // [B,S,H] int8-in-int32
    const float* scale = (const float*)d_in[1]; // [T]
    const int* w1 = (const int*)d_in[2];        // [I,H]
    const float* w1s = (const float*)d_in[3];   // [I]
    const float* b1 = (const float*)d_in[4];    // [I]
    const int* w2 = (const int*)d_in[5];        // [H,I]
    const float* w2s = (const float*)d_in[6];   // [H]
    const float* b2 = (const float*)d_in[7];    // [H]

    char* ws = (char*)d_ws;
    signed char* xq = (signed char*)ws;                     // 26,214,400 B
    signed char* w1q = xq + (size_t)T_DIM * H_DIM;          // 40,960,000 B
    signed char* w2q = w1q + (size_t)I_DIM * H_DIM;         // 40,960,000 B
    _Float16* fc1h = (_Float16*)(w2q + (size_t)H_DIM * I_DIM);  // chunkT*I fp16
    const size_t fixed = (size_t)T_DIM * H_DIM + 2 * (size_t)I_DIM * H_DIM;

    // choose smallest chunk count whose workspace fits ws_size (deterministic)
    int nc = 1;
    while (nc < 16) {
        size_t need = fixed + ((size_t)T_DIM / nc) * I_DIM * 2 +
                      ((size_t)T_DIM / nc) * 4 + 256;
        if (need <= ws_size) break;
        nc <<= 1;
    }
    const int chunkT = T_DIM / nc;
    float* nscale = (float*)((char*)fc1h + (size_t)chunkT * I_DIM * 2);

    repack_kernel<<<2048, 256, 0, stream>>>(hs, (unsigned int*)xq, (long)T_DIM * H_DIM / 4);
    repack_kernel<<<2048, 256, 0, stream>>>(w1, (unsigned int*)w1q, (long)I_DIM * H_DIM / 4);
    repack_kernel<<<2048, 256, 0, stream>>>(w2, (unsigned int*)w2q, (long)H_DIM * I_DIM / 4);

    const int n2tiles = (H_DIM + 255) / 256;  // 13; last tile col-guarded
    for (int c = 0; c < nc; ++c) {
        const int t0 = c * chunkT;
        gemm_i8_2cu<0><<<dim3(chunkT / 128, I_DIM / 256), 512, 0, stream>>>(
            xq + (size_t)t0 * H_DIM, (long)H_DIM, w1q, (long)H_DIM,
            I_DIM, H_DIM, I_DIM,
            scale + t0, w1s, b1, (void*)fc1h);
        gelu_quant<<<chunkT, 320, 0, stream>>>(fc1h, nscale);
        gemm_i8_2cu<1><<<dim3(chunkT / 128, n2tiles), 512, 0, stream>>>(
            (const signed char*)fc1h, (long)I_DIM * 2, w2q, (long)I_DIM,
            H_DIM, I_DIM, H_DIM,
            nscale, w2s, b2,
            (void*)((float*)d_out + (size_t)t0 * H_DIM));
    }
}

// Round 12
// 950.218 us; speedup vs baseline: 1.1604x; 1.1604x over previous
//
#include <hip/hip_runtime.h>
#include <hip/hip_bf16.h>
#include <hip/hip_fp16.h>

#define T_DIM 8192
#define H_DIM 3200
#define I_DIM 12800

typedef int v4i __attribute__((ext_vector_type(4)));
typedef _Float16 h8 __attribute__((ext_vector_type(8)));

__device__ __forceinline__ void gload16(const void* g, void* l) {
    __builtin_amdgcn_global_load_lds(
        (const __attribute__((address_space(1))) unsigned int*)g,
        (__attribute__((address_space(3))) unsigned int*)l, 16, 0, 0);
}

// ---------------- int32 -> int8 repack (memory-bound) ----------------
__global__ __launch_bounds__(256) void repack_kernel(const int* __restrict__ src,
                                                     unsigned int* __restrict__ dst,
                                                     long n4) {
    long i = (long)blockIdx.x * blockDim.x + threadIdx.x;
    long stride = (long)gridDim.x * blockDim.x;
    for (; i < n4; i += stride) {
        int4 v = ((const int4*)src)[i];
        dst[i] = (unsigned int)((v.x & 255) | ((v.y & 255) << 8) |
                                ((v.z & 255) << 16) | ((v.w & 255) << 24));
    }
}

// ---------------- i8 GEMM, C[M][N] = A[M][K] * B[N][K]^T ----------------
// SESSION-BEST STRUCTURE (round 9: 948 us total, 379 us/GEMM, MfmaUtil 41.5%,
// restored verbatim after R10 pair-phase = null and R11 2-block split =
// regression). 256x256 tile, 1024 threads = 16 waves (4M x 4N), per-wave
// 64x64 via mfma_i32_16x16x64_i8 -> acc[4][4] = 64 AGPR + ~56 VGPR fits the
// 128-reg cap of 4 waves/SIMD (R8 showed 8-wave/128x64 spills catastrophically
// under the same cap). 4 waves/SIMD hides phase-boundary latency (+5% vs
// 2 waves/SIMD, the only occupancy win that reproduced).
// One phase per 64-byte K-half h:
//   { 8 ds_read_b128 (af[4], bf[4]) ; STAGE A(h+3)+B(h+3) (2 gload16/thread)
//     ; setprio1 ; 16 MFMA ; setprio0 ; vmcnt(4) ; ONE s_barrier }
// Ring-of-4 LDS slots/operand (128 KiB). Ledger (2 loads per A+B unit-pair):
// prologue stages halves 0,1,2 (6 in flight), gate vmcnt(4) -> half 0
// resident. Phase h stages h+3 (in flight h+1,h+2,h+3 = 6), gate retires
// h+1 -> entering h+1: resident h+1, in flight 4. Never drained to 0.
// Slot safety (skew <= 1 phase): STAGE(h+3) writes slot (h-1)&3 after the
// stager crossed barrier h-1; all readers of half h-1 completed their
// ds_reads before crossing that same barrier (MFMAs consumed them).
// LDS dest of global_load_lds is LINEAR; XOR swizzle (16B chunk
// cc ^= (row>>1)&3) pre-applied to per-lane GLOBAL source and ds_read addrs
// (0-conflict, measured). strideA/strideB in BYTES. EPI=0: fp16 out;
// EPI=1: fp32 of fp16-rounded. fc2's N=3200 runs on 13 col-guarded tiles.
// No XCD swizzle (L3-resident regime: tripled FETCH_SIZE in round 2).
// Known structural ceiling at this design point: per phase per CU the LDS
// port moves 128 KiB (~1800 cyc incl. staged writes) vs 1307 cyc of MFMA;
// lower bytes/op requires a larger per-wave acc, blocked by the 128-reg cap.
template <int EPI>
__global__ __launch_bounds__(1024, 4) void gemm_i8_16w(
    const signed char* __restrict__ A, long strideA,
    const signed char* __restrict__ B, long strideB,
    int Ntrue, int K, int ldc,
    const float* __restrict__ rowscale, const float* __restrict__ colscale,
    const float* __restrict__ bias, void* __restrict__ Cout) {
    __shared__ signed char lds[131072];
    signed char* ldsA = lds;           // 4 units x 16384 B (256 rows x 64 B)
    signed char* ldsB = lds + 65536;   // 4 units x 16384 B

    const int tid = threadIdx.x;
    const int lane = tid & 63, wid = tid >> 6;
    const int wr = wid >> 2, wc = wid & 3;
    const int bm = blockIdx.x, bn = blockIdx.y;
    const long Arow0 = (long)bm * 256;
    const long Bcol0 = (long)bn * 256;

    // Staging: unit = 256 rows x 64 B = 1024 chunks of 16 B; thread handles
    // chunk tid. LDS dest is linear (chunk*16); swizzle folded into the
    // per-lane GLOBAL source chunk.
    const int r0 = tid >> 2;
    const int s0 = (((tid & 3) ^ ((r0 >> 1) & 3)) << 4);
    const signed char* Ag0 = A + (Arow0 + r0) * strideA + s0;
    const signed char* Bg0 = B + (Bcol0 + r0) * strideB + s0;
    const int d0 = tid * 16;

    const int NH = K >> 6;  // number of 64-byte K-halves (phases)

#define STAGE_AB(h)                                 \
    {                                               \
        const int hc_ = (h) < NH ? (h) : NH - 1;    \
        const long ko_ = (long)hc_ << 6;            \
        const int sl_ = ((h) & 3) << 14;            \
        gload16(Ag0 + ko_, ldsA + sl_ + d0);        \
        gload16(Bg0 + ko_, ldsB + sl_ + d0);        \
    }

    // Fragment read offsets: lane reads 16 B at (row, k-chunk q) -> LDS chunk
    // q ^ ((row>>1)&3); per-lane constant swz. Frag i lives at +i*1024.
    const int r = lane & 15, q = lane >> 4;
    const int swz = ((q ^ ((r >> 1) & 3)) << 4);
    const int aoff = (wr * 64 + r) * 64 + swz;  // + i*1024, i = 0..3
    const int boff = (wc * 64 + r) * 64 + swz;  // + n*1024, n = 0..3

    v4i acc[4][4] = {};
    v4i af[4], bf[4];

    // Prologue: stage halves 0,1,2 (6 loads); gate to 4 -> half 0 resident,
    // halves 1,2 in flight.
    STAGE_AB(0); STAGE_AB(1); STAGE_AB(2);
    asm volatile("s_waitcnt vmcnt(4)");
    __builtin_amdgcn_s_barrier();

    for (int h = 0; h < NH; ++h) {
        const signed char* sA = ldsA + ((h & 3) << 14);
        const signed char* sB = ldsB + ((h & 3) << 14);
#pragma unroll
        for (int i = 0; i < 4; ++i) af[i] = *(const v4i*)(sA + aoff + i * 1024);
#pragma unroll
        for (int n = 0; n < 4; ++n) bf[n] = *(const v4i*)(sB + boff + n * 1024);
        // stage half h+3 into slot (h+3)&3 = (h-1)&3 (readers done before the
        // end-of-(h-1) barrier the stager has crossed).
        STAGE_AB(h + 3);
        __builtin_amdgcn_s_setprio(1);
#pragma unroll
        for (int m = 0; m < 4; ++m)
#pragma unroll
            for (int n = 0; n < 4; ++n)
                acc[m][n] = __builtin_amdgcn_mfma_i32_16x16x64_i8(
                    af[m], bf[n], acc[m][n], 0, 0, 0);
        __builtin_amdgcn_s_setprio(0);
        // counted gate: retire half h+1's pair; leave h+2,h+3 (4) in flight.
        asm volatile("s_waitcnt vmcnt(4)");
        __builtin_amdgcn_s_barrier();
    }

    // Epilogue: C/D layout col = lane&15, row = (lane>>4)*4 + reg.
    const int row0 = bm * 256 + wr * 64;
    const int col0 = bn * 256 + wc * 64;
    const int r4 = (lane >> 4) << 2, cl = lane & 15;
#pragma unroll
    for (int m = 0; m < 4; ++m) {
        const int rowb = row0 + m * 16 + r4;
        float rs[4];
#pragma unroll
        for (int rr = 0; rr < 4; ++rr) rs[rr] = rowscale[rowb + rr];
#pragma unroll
        for (int n = 0; n < 4; ++n) {
            const int col = col0 + n * 16 + cl;
            if (col < Ntrue) {
                const float cs = colscale[col];
                const float bs = bias[col];
#pragma unroll
                for (int rr = 0; rr < 4; ++rr) {
                    float v = (float)acc[m][n][rr];
                    v = __fmul_rn(v, rs[rr]);
                    v = __fmul_rn(v, cs);
                    v = __fadd_rn(v, bs);
                    _Float16 hh = (_Float16)v;  // reference rounds to fp16
                    const size_t idx = (size_t)(rowb + rr) * ldc + col;
                    if (EPI == 0) ((_Float16*)Cout)[idx] = hh;
                    else ((float*)Cout)[idx] = (float)hh;
                }
            }
        }
    }
#undef STAGE_AB
}

// -------- exact GELU + per-token dynamic int8 requant (in-place act_q) -------
// R9's LDS-buffered version (the R11 register-resident variant regressed
// ~80 us in the non-GEMM residual; reverted).
__global__ __launch_bounds__(256) void gelu_quant(_Float16* __restrict__ fc1,
                                                  float* __restrict__ nscale) {
    __shared__ float gbuf[I_DIM];
    __shared__ float wmax[4];
    const int tid = threadIdx.x, lane = tid & 63, wid = tid >> 6;
    const long t = blockIdx.x;
    const h8* row = (const h8*)(fc1 + t * I_DIM);
    float lmax = 0.f;
    for (int c = tid; c < I_DIM / 8; c += 256) {
        h8 v = row[c];
#pragma unroll
        for (int j = 0; j < 8; ++j) {
            float x = (float)v[j];
            // jax.nn.gelu exact: 0.5*x*(1+erf(x/sqrt(2))), no FMA contraction
            float e = erff(__fdiv_rn(x, 1.41421356237309504880f));
            float g = __fmul_rn(__fmul_rn(0.5f, x), __fadd_rn(1.0f, e));
            gbuf[c * 8 + j] = g;
            lmax = fmaxf(lmax, fabsf(g));
        }
    }
#pragma unroll
    for (int off = 32; off; off >>= 1) lmax = fmaxf(lmax, __shfl_xor(lmax, off, 64));
    if (lane == 0) wmax[wid] = lmax;
    __syncthreads();
    const float gmax = fmaxf(fmaxf(wmax[0], wmax[1]), fmaxf(wmax[2], wmax[3]));
    const float ns = gmax / 127.0f;
    if (tid == 0) nscale[t] = ns;
    unsigned long long* out = (unsigned long long*)(fc1 + t * I_DIM);  // in-place
    for (int c = tid; c < I_DIM / 8; c += 256) {
        unsigned long long pk = 0;
#pragma unroll
        for (int j = 0; j < 8; ++j) {
            float qv = rintf(__fdiv_rn(gbuf[c * 8 + j], ns));  // RNE == jnp.round
            qv = fminf(fmaxf(qv, -127.f), 127.f);
            pk |= ((unsigned long long)(unsigned char)(signed char)(int)qv) << (8 * j);
        }
        out[c] = pk;
    }
}

extern "C" void kernel_launch(void* const* d_in, const int* in_sizes, int n_in,
                              void* d_out, int out_size, void* d_ws, size_t ws_size,
                              hipStream_t stream) {
    const int* hs = (const int*)d_in[0];        // [B,S,H] int8-in-int32
    const float* scale = (const float*)d_in[1]; // [T]
    const int* w1 = (const int*)d_in[2];        // [I,H]
    const float* w1s = (const float*)d_in[3];   // [I]
    const float* b1 = (const float*)d_in[4];    // [I]
    const int* w2 = (const int*)d_in[5];        // [H,I]
    const float* w2s = (const float*)d_in[6];   // [H]
    const float* b2 = (const float*)d_in[7];    // [H]

    char* ws = (char*)d_ws;
    signed char* xq = (signed char*)ws;                     // 26,214,400 B
    signed char* w1q = xq + (size_t)T_DIM * H_DIM;          // 40,960,000 B
    signed char* w2q = w1q + (size_t)I_DIM * H_DIM;         // 40,960,000 B
    _Float16* fc1h = (_Float16*)(w2q + (size_t)H_DIM * I_DIM);  // chunkT*I fp16
    const size_t fixed = (size_t)T_DIM * H_DIM + 2 * (size_t)I_DIM * H_DIM;

    // choose smallest chunk count whose workspace fits ws_size (deterministic)
    int nc = 1;
    while (nc < 16) {
        size_t need = fixed + ((size_t)T_DIM / nc) * I_DIM * 2 +
                      ((size_t)T_DIM / nc) * 4 + 256;
        if (need <= ws_size) break;
        nc <<= 1;
    }
    const int chunkT = T_DIM / nc;
    float* nscale = (float*)((char*)fc1h + (size_t)chunkT * I_DIM * 2);

    repack_kernel<<<2048, 256, 0, stream>>>(hs, (unsigned int*)xq, (long)T_DIM * H_DIM / 4);
    repack_kernel<<<2048, 256, 0, stream>>>(w1, (unsigned int*)w1q, (long)I_DIM * H_DIM / 4);
    repack_kernel<<<2048, 256, 0, stream>>>(w2, (unsigned int*)w2q, (long)H_DIM * I_DIM / 4);

    const int n2tiles = (H_DIM + 255) / 256;  // 13; last tile col-guarded
    for (int c = 0; c < nc; ++c) {
        const int t0 = c * chunkT;
        gemm_i8_16w<0><<<dim3(chunkT / 256, I_DIM / 256), 1024, 0, stream>>>(
            xq + (size_t)t0 * H_DIM, (long)H_DIM, w1q, (long)H_DIM,
            I_DIM, H_DIM, I_DIM,
            scale + t0, w1s, b1, (void*)fc1h);
        gelu_quant<<<chunkT, 256, 0, stream>>>(fc1h, nscale);
        gemm_i8_16w<1><<<dim3(chunkT / 256, n2tiles), 1024, 0, stream>>>(
            (const signed char*)fc1h, (long)I_DIM * 2, w2q, (long)I_DIM,
            H_DIM, I_DIM, H_DIM,
            nscale, w2s, b2,
            (void*)((float*)d_out + (size_t)t0 * H_DIM));
    }
}

// Round 13
// 935.666 us; speedup vs baseline: 1.1785x; 1.0156x over previous
//
#include <hip/hip_runtime.h>
#include <hip/hip_bf16.h>
#include <hip/hip_fp16.h>

#define T_DIM 8192
#define H_DIM 3200
#define I_DIM 12800

typedef int v4i __attribute__((ext_vector_type(4)));
typedef _Float16 h8 __attribute__((ext_vector_type(8)));

__device__ __forceinline__ void gload16(const void* g, void* l) {
    __builtin_amdgcn_global_load_lds(
        (const __attribute__((address_space(1))) unsigned int*)g,
        (__attribute__((address_space(3))) unsigned int*)l, 16, 0, 0);
}

// ------- int32 -> int8 repack, all three tensors in ONE launch -------
__device__ __forceinline__ void repack_range(const int* __restrict__ src,
                                             unsigned int* __restrict__ dst,
                                             long n4, long i0, long stride) {
    for (long i = i0; i < n4; i += stride) {
        int4 v = ((const int4*)src)[i];
        dst[i] = (unsigned int)((v.x & 255) | ((v.y & 255) << 8) |
                                ((v.z & 255) << 16) | ((v.w & 255) << 24));
    }
}

__global__ __launch_bounds__(256) void repack3(
    const int* __restrict__ s0, unsigned int* __restrict__ d0, long n0,
    const int* __restrict__ s1, unsigned int* __restrict__ d1, long n1,
    const int* __restrict__ s2, unsigned int* __restrict__ d2, long n2) {
    const long i0 = (long)blockIdx.x * blockDim.x + threadIdx.x;
    const long stride = (long)gridDim.x * blockDim.x;
    repack_range(s0, d0, n0, i0, stride);
    repack_range(s1, d1, n1, i0, stride);
    repack_range(s2, d2, n2, i0, stride);
}

// ---------------- i8 GEMM, C[M][N] = A[M][K] * B[N][K]^T ----------------
// SESSION-BEST STRUCTURE (rounds 9/12: 948/950 us total, 379 us/GEMM,
// MfmaUtil 41.5%). 256x256 tile, 1024 threads = 16 waves (4M x 4N), per-wave
// 64x64 via mfma_i32_16x16x64_i8 -> acc[4][4] = 64 AGPR + ~56 VGPR fits the
// 128-reg cap of 4 waves/SIMD (R8 showed 8-wave/128x64 spills catastrophically
// under the same cap). 4 waves/SIMD hides phase-boundary latency (+5% vs
// 2 waves/SIMD, the only occupancy win that reproduced).
// One phase per 64-byte K-half h:
//   { 8 ds_read_b128 (af[4], bf[4]) ; STAGE A(h+3)+B(h+3) (2 gload16/thread)
//     ; setprio1 ; 16 MFMA ; setprio0 ; vmcnt(4) ; ONE s_barrier }
// Ring-of-4 LDS slots/operand (128 KiB). Ledger (2 loads per A+B unit-pair):
// prologue stages halves 0,1,2 (6 in flight), gate vmcnt(4) -> half 0
// resident. Phase h stages h+3 (in flight h+1,h+2,h+3 = 6), gate retires
// h+1 -> entering h+1: resident h+1, in flight 4. Never drained to 0.
// Slot safety (skew <= 1 phase): STAGE(h+3) writes slot (h-1)&3 after the
// stager crossed barrier h-1; all readers of half h-1 completed their
// ds_reads before crossing that same barrier (MFMAs consumed them).
// Tail clamp REMOVED (R13): stages for halves >= NH read <= 192 B past the
// operand row / region end -- audited to land inside d_ws for all four
// operand cases (fc1-A -> w1q, fc1-B -> w2q, fc2-A stays in-row since
// ko <= 12928 < strideA 25600, fc2-B -> fc1h). Those slots are never read
// (loop ends at h = NH-1). Saves the per-phase cmp/cndmask clamp chain.
// LDS dest of global_load_lds is LINEAR; XOR swizzle (16B chunk
// cc ^= (row>>1)&3) pre-applied to per-lane GLOBAL source and ds_read addrs
// (0-conflict, measured). strideA/strideB in BYTES. EPI=0: fp16 out;
// EPI=1: fp32 of fp16-rounded. fc2's N=3200 runs on 13 col-guarded tiles.
// No XCD swizzle (L3-resident regime: tripled FETCH_SIZE in round 2).
// Known structural ceiling at this design point: per phase per CU the LDS
// port moves 128 KiB (~1800 cyc incl. staged writes) vs 1307 cyc of MFMA;
// measured 2900 cyc/phase; the gap resisted every catalogued source-level
// schedule variant (9 structural rounds).
template <int EPI>
__global__ __launch_bounds__(1024, 4) void gemm_i8_16w(
    const signed char* __restrict__ A, long strideA,
    const signed char* __restrict__ B, long strideB,
    int Ntrue, int K, int ldc,
    const float* __restrict__ rowscale, const float* __restrict__ colscale,
    const float* __restrict__ bias, void* __restrict__ Cout) {
    __shared__ signed char lds[131072];
    signed char* ldsA = lds;           // 4 units x 16384 B (256 rows x 64 B)
    signed char* ldsB = lds + 65536;   // 4 units x 16384 B

    const int tid = threadIdx.x;
    const int lane = tid & 63, wid = tid >> 6;
    const int wr = wid >> 2, wc = wid & 3;
    const int bm = blockIdx.x, bn = blockIdx.y;
    const long Arow0 = (long)bm * 256;
    const long Bcol0 = (long)bn * 256;

    // Staging: unit = 256 rows x 64 B = 1024 chunks of 16 B; thread handles
    // chunk tid. LDS dest is linear (chunk*16); swizzle folded into the
    // per-lane GLOBAL source chunk.
    const int r0 = tid >> 2;
    const int s0 = (((tid & 3) ^ ((r0 >> 1) & 3)) << 4);
    const signed char* Ag0 = A + (Arow0 + r0) * strideA + s0;
    const signed char* Bg0 = B + (Bcol0 + r0) * strideB + s0;
    const int d0 = tid * 16;

    const int NH = K >> 6;  // number of 64-byte K-halves (phases)

#define STAGE_AB(h)                                 \
    {                                               \
        const long ko_ = (long)(h) << 6;            \
        const int sl_ = ((h) & 3) << 14;            \
        gload16(Ag0 + ko_, ldsA + sl_ + d0);        \
        gload16(Bg0 + ko_, ldsB + sl_ + d0);        \
    }

    // Fragment read offsets: lane reads 16 B at (row, k-chunk q) -> LDS chunk
    // q ^ ((row>>1)&3); per-lane constant swz. Frag i lives at +i*1024.
    const int r = lane & 15, q = lane >> 4;
    const int swz = ((q ^ ((r >> 1) & 3)) << 4);
    const int aoff = (wr * 64 + r) * 64 + swz;  // + i*1024, i = 0..3
    const int boff = (wc * 64 + r) * 64 + swz;  // + n*1024, n = 0..3

    v4i acc[4][4] = {};
    v4i af[4], bf[4];

    // Prologue: stage halves 0,1,2 (6 loads); gate to 4 -> half 0 resident,
    // halves 1,2 in flight.
    STAGE_AB(0); STAGE_AB(1); STAGE_AB(2);
    asm volatile("s_waitcnt vmcnt(4)");
    __builtin_amdgcn_s_barrier();

    for (int h = 0; h < NH; ++h) {
        const signed char* sA = ldsA + ((h & 3) << 14);
        const signed char* sB = ldsB + ((h & 3) << 14);
#pragma unroll
        for (int i = 0; i < 4; ++i) af[i] = *(const v4i*)(sA + aoff + i * 1024);
#pragma unroll
        for (int n = 0; n < 4; ++n) bf[n] = *(const v4i*)(sB + boff + n * 1024);
        // stage half h+3 into slot (h+3)&3 = (h-1)&3 (readers done before the
        // end-of-(h-1) barrier the stager has crossed). Tail stages (h+3 >=
        // NH) read harmless in-ws bytes into slots that are never consumed.
        STAGE_AB(h + 3);
        __builtin_amdgcn_s_setprio(1);
#pragma unroll
        for (int m = 0; m < 4; ++m)
#pragma unroll
            for (int n = 0; n < 4; ++n)
                acc[m][n] = __builtin_amdgcn_mfma_i32_16x16x64_i8(
                    af[m], bf[n], acc[m][n], 0, 0, 0);
        __builtin_amdgcn_s_setprio(0);
        // counted gate: retire half h+1's pair; leave h+2,h+3 (4) in flight.
        asm volatile("s_waitcnt vmcnt(4)");
        __builtin_amdgcn_s_barrier();
    }

    // Epilogue: C/D layout col = lane&15, row = (lane>>4)*4 + reg.
    const int row0 = bm * 256 + wr * 64;
    const int col0 = bn * 256 + wc * 64;
    const int r4 = (lane >> 4) << 2, cl = lane & 15;
#pragma unroll
    for (int m = 0; m < 4; ++m) {
        const int rowb = row0 + m * 16 + r4;
        float rs[4];
#pragma unroll
        for (int rr = 0; rr < 4; ++rr) rs[rr] = rowscale[rowb + rr];
#pragma unroll
        for (int n = 0; n < 4; ++n) {
            const int col = col0 + n * 16 + cl;
            if (col < Ntrue) {
                const float cs = colscale[col];
                const float bs = bias[col];
#pragma unroll
                for (int rr = 0; rr < 4; ++rr) {
                    float v = (float)acc[m][n][rr];
                    v = __fmul_rn(v, rs[rr]);
                    v = __fmul_rn(v, cs);
                    v = __fadd_rn(v, bs);
                    _Float16 hh = (_Float16)v;  // reference rounds to fp16
                    const size_t idx = (size_t)(rowb + rr) * ldc + col;
                    if (EPI == 0) ((_Float16*)Cout)[idx] = hh;
                    else ((float*)Cout)[idx] = (float)hh;
                }
            }
        }
    }
#undef STAGE_AB
}

// -------- exact GELU + per-token dynamic int8 requant (in-place act_q) -------
// LDS-buffered version (register-resident variant regressed in R11; kept).
__global__ __launch_bounds__(256) void gelu_quant(_Float16* __restrict__ fc1,
                                                  float* __restrict__ nscale) {
    __shared__ float gbuf[I_DIM];
    __shared__ float wmax[4];
    const int tid = threadIdx.x, lane = tid & 63, wid = tid >> 6;
    const long t = blockIdx.x;
    const h8* row = (const h8*)(fc1 + t * I_DIM);
    float lmax = 0.f;
    for (int c = tid; c < I_DIM / 8; c += 256) {
        h8 v = row[c];
#pragma unroll
        for (int j = 0; j < 8; ++j) {
            float x = (float)v[j];
            // jax.nn.gelu exact: 0.5*x*(1+erf(x/sqrt(2))), no FMA contraction
            float e = erff(__fdiv_rn(x, 1.41421356237309504880f));
            float g = __fmul_rn(__fmul_rn(0.5f, x), __fadd_rn(1.0f, e));
            gbuf[c * 8 + j] = g;
            lmax = fmaxf(lmax, fabsf(g));
        }
    }
#pragma unroll
    for (int off = 32; off; off >>= 1) lmax = fmaxf(lmax, __shfl_xor(lmax, off, 64));
    if (lane == 0) wmax[wid] = lmax;
    __syncthreads();
    const float gmax = fmaxf(fmaxf(wmax[0], wmax[1]), fmaxf(wmax[2], wmax[3]));
    const float ns = gmax / 127.0f;
    if (tid == 0) nscale[t] = ns;
    unsigned long long* out = (unsigned long long*)(fc1 + t * I_DIM);  // in-place
    for (int c = tid; c < I_DIM / 8; c += 256) {
        unsigned long long pk = 0;
#pragma unroll
        for (int j = 0; j < 8; ++j) {
            float qv = rintf(__fdiv_rn(gbuf[c * 8 + j], ns));  // RNE == jnp.round
            qv = fminf(fmaxf(qv, -127.f), 127.f);
            pk |= ((unsigned long long)(unsigned char)(signed char)(int)qv) << (8 * j);
        }
        out[c] = pk;
    }
}

extern "C" void kernel_launch(void* const* d_in, const int* in_sizes, int n_in,
                              void* d_out, int out_size, void* d_ws, size_t ws_size,
                              hipStream_t stream) {
    const int* hs = (const int*)d_in[0];        // [B,S,H] int8-in-int32
    const float* scale = (const float*)d_in[1]; // [T]
    const int* w1 = (const int*)d_in[2];        // [I,H]
    const float* w1s = (const float*)d_in[3];   // [I]
    const float* b1 = (const float*)d_in[4];    // [I]
    const int* w2 = (const int*)d_in[5];        // [H,I]
    const float* w2s = (const float*)d_in[6];   // [H]
    const float* b2 = (const float*)d_in[7];    // [H]

    char* ws = (char*)d_ws;
    signed char* xq = (signed char*)ws;                     // 26,214,400 B
    signed char* w1q = xq + (size_t)T_DIM * H_DIM;          // 40,960,000 B
    signed char* w2q = w1q + (size_t)I_DIM * H_DIM;         // 40,960,000 B
    _Float16* fc1h = (_Float16*)(w2q + (size_t)H_DIM * I_DIM);  // chunkT*I fp16
    const size_t fixed = (size_t)T_DIM * H_DIM + 2 * (size_t)I_DIM * H_DIM;

    // choose smallest chunk count whose workspace fits ws_size (deterministic)
    int nc = 1;
    while (nc < 16) {
        size_t need = fixed + ((size_t)T_DIM / nc) * I_DIM * 2 +
                      ((size_t)T_DIM / nc) * 4 + 256;
        if (need <= ws_size) break;
        nc <<= 1;
    }
    const int chunkT = T_DIM / nc;
    float* nscale = (float*)((char*)fc1h + (size_t)chunkT * I_DIM * 2);

    // single launch for all three repacks (saves 2 launch/drain gaps)
    repack3<<<2048, 256, 0, stream>>>(
        hs, (unsigned int*)xq, (long)T_DIM * H_DIM / 4,
        w1, (unsigned int*)w1q, (long)I_DIM * H_DIM / 4,
        w2, (unsigned int*)w2q, (long)H_DIM * I_DIM / 4);

    const int n2tiles = (H_DIM + 255) / 256;  // 13; last tile col-guarded
    for (int c = 0; c < nc; ++c) {
        const int t0 = c * chunkT;
        gemm_i8_16w<0><<<dim3(chunkT / 256, I_DIM / 256), 1024, 0, stream>>>(
            xq + (size_t)t0 * H_DIM, (long)H_DIM, w1q, (long)H_DIM,
            I_DIM, H_DIM, I_DIM,
            scale + t0, w1s, b1, (void*)fc1h);
        gelu_quant<<<chunkT, 256, 0, stream>>>(fc1h, nscale);
        gemm_i8_16w<1><<<dim3(chunkT / 256, n2tiles), 1024, 0, stream>>>(
            (const signed char*)fc1h, (long)I_DIM * 2, w2q, (long)I_DIM,
            H_DIM, I_DIM, H_DIM,
            nscale, w2s, b2,
            (void*)((float*)d_out + (size_t)t0 * H_DIM));
    }
}